// Round 9
// baseline (99.018 us; speedup 1.0000x reference)
//
#include <hip/hip_runtime.h>

// Batched 10-qubit statevector simulator — TWO 64-lane waves per sample (R8).
// State: 1024 complex amps; s = (h<<9)|(rl<<6)|lane; qubit q <-> bit (9-q):
//   qubit 0      -> wave half h (threadIdx.x>>6), 8 f2 registers per lane
//   qubits 1..3  -> register-index bits rl (8 complex float2 per lane)
//   qubits 4..9  -> lane bits (butterfly exchanges)
// Per layer per qubit, RY(a)RZ(b)RZ(g)RY(d) fuse into one SU(2)
// U = [[u, -conj(v)],[v, conj(u)]], p=(b+g)/2.
// R1/R2: 50 gate coefficient sets lane-parallel, broadcast via v_readlane.
// R3: CNOT chain (3,4)..(8,9) fused to one ds_bpermute pass
//     (dest lane d pulls s = (d^(d>>1)) ^ ((r&1)<<5)).
// R4: float2 state -> VOP3P v_pk_fma_f32.
// R5: masks 1,2 (quad_perm) and 8 (row_ror:8) via DPP on the VALU pipe.
// R7 post-mortem: kernel is VALU-ISSUE-bound at 4 waves/SIMD (71K VALU cycles
//     = 61% busy); permlane swaps regressed (added VALU, DS was hidden).
// R8: split each sample across 2 waves -> 8192 waves = 8/SIMD to fill the
//     39% idle. Only the q0 gate is cross-wave: one 8-register LDS exchange
//     + 2 barriers per layer. CNOT(0,1) (ctrl=r3) = wave-uniform swap;
//     CNOT(9,0) (tgt=r3) absorbed into next layer's q0 operand select and
//     the epilogue z0 sign (h ^ lane&1).

constexpr int NQ  = 10;
constexpr int NL  = 5;
constexpr int OBS = 10;

typedef float f2 __attribute__((ext_vector_type(2)));

__device__ __forceinline__ float readlane_f(float v, int l) {
    return __int_as_float(__builtin_amdgcn_readlane(__float_as_int(v), l));
}
__device__ __forceinline__ float bperm_f(int byte_addr, float v) {
    return __int_as_float(__builtin_amdgcn_ds_bpermute(byte_addr, __float_as_int(v)));
}
template <int CTRL>
__device__ __forceinline__ float dpp_f(float v) {
    return __int_as_float(__builtin_amdgcn_update_dpp(
        0, __float_as_int(v), CTRL, 0xF, 0xF, true));
}
// xor-exchange across lanes; M constant after unroll -> branches fold.
__device__ __forceinline__ float xor_lane(float v, int M,
                                          int a4, int a16, int a32) {
    switch (M) {
    case 1:  return dpp_f<0xB1>(v);          // quad_perm [1,0,3,2]
    case 2:  return dpp_f<0x4E>(v);          // quad_perm [2,3,0,1]
    case 8:  return dpp_f<0x128>(v);         // row_ror:8 == lane^8
    case 4:  return bperm_f(a4,  v);
    case 16: return bperm_f(a16, v);
    default: return bperm_f(a32, v);         // 32
    }
}

__global__ __launch_bounds__(128, 8) void qsim_kernel(
    const float* __restrict__ x,       // (B, 10)
    const float* __restrict__ isc,     // (5, 20)
    const float* __restrict__ w,       // (5, 20)
    const float* __restrict__ oscale,  // (4)
    float* __restrict__ out)           // (B, 4)
{
    __shared__ f2    sh[1024];   // [h][rl][lane] exchange buffer (8 KB)
    __shared__ float red[8];     // cross-wave reduction

    const int lane = threadIdx.x & 63;
    const int h    = threadIdx.x >> 6;     // wave half = qubit-0 bit
    const int wid  = blockIdx.x;           // one sample per block

    // ---- lane-parallel gate-coefficient computation (gates 0..49) ----
    float cUR, cUI, cVR, cVI;
    {
        const int g   = (lane < 50) ? lane : 49;
        const int q   = g % 10;
        const int lyr = g / 10;
        const float xq    = x[wid * OBS + q];
        const float alpha = isc[lyr * 2 * NQ + q]      * xq;
        const float beta  = isc[lyr * 2 * NQ + NQ + q] * xq;
        const float gamma = w[lyr * 2 * NQ + q];
        const float delta = w[lyr * 2 * NQ + NQ + q];
        float sa, ca, sp, cp, sd, cd;
        __sincosf(0.5f * alpha,          &sa, &ca);
        __sincosf(0.5f * (beta + gamma), &sp, &cp);
        __sincosf(0.5f * delta,          &sd, &cd);
        const float A = cd * ca, Bt = sd * sa;
        const float C = cd * sa, D  = sd * ca;
        cUR = (A - Bt) * cp;
        cUI = -(A + Bt) * sp;
        cVR = (C + D) * cp;
        cVI = (C - D) * sp;
    }

    // hoisted bpermute byte-addresses (loop-invariant)
    const int a4  = (lane ^ 4)  * 4;
    const int a16 = (lane ^ 16) * 4;
    const int a32 = (lane ^ 32) * 4;
    const int cnot_src  = (lane ^ (lane >> 1));
    const int addr_even = cnot_src * 4;            // rl bit0 == 0
    const int addr_odd  = (cnot_src ^ 32) * 4;     // rl bit0 == 1 (CNOT(3,4))

    f2 c[8];
#pragma unroll
    for (int r = 0; r < 8; ++r) c[r] = (f2){0.f, 0.f};
    if (h == 0) c[0].x = (lane == 0) ? 1.f : 0.f;   // |0...0>

#define SWAPR(i, j) { f2 _t = c[i]; c[i] = c[j]; c[j] = _t; }

    for (int layer = 0; layer < NL; ++layer) {
        const int base = layer * NQ;   // wave-uniform

        // ===== q = 0 gate (cross-wave) + pending CNOT(9,0) =====
        {
            const float ur = readlane_f(cUR, base + 0);
            const float ui = readlane_f(cUI, base + 0);
            const float vr = readlane_f(cVR, base + 0);
            const float vi = readlane_f(cVI, base + 0);
            const f2 kUU  = {ur, ur};
            const f2 kUIm = {-ui, ui};
            const f2 kVVn = {-vr, -vr};
            const f2 kVV  = {vr, vr};
            const f2 kVIm = {-vi, vi};
            const f2 kUIp = {ui, -ui};

#pragma unroll
            for (int r = 0; r < 8; ++r) sh[h * 512 + r * 64 + lane] = c[r];
            __syncthreads();
            f2 p[8];
#pragma unroll
            for (int r = 0; r < 8; ++r) p[r] = sh[(1 - h) * 512 + r * 64 + lane];
            __syncthreads();   // buffer free for next layer's writes

            // pending CNOT(9,0) from previous layer: for odd lanes the two
            // halves are swapped before the gate (layer 0 has none).
            const bool swp = (layer != 0) && ((lane & 1) != 0);
            if (h == 0) {
#pragma unroll
                for (int r = 0; r < 8; ++r) {
                    const f2 a = c[r], b = p[r];
                    const f2 X0 = swp ? b : a;       // bit3=0 slot
                    const f2 X1 = swp ? a : b;       // bit3=1 slot
                    c[r] = kUU*X0 + kUIm*X0.yx + kVVn*X1 + kVIm*X1.yx;
                }
            } else {
#pragma unroll
                for (int r = 0; r < 8; ++r) {
                    const f2 a = c[r], b = p[r];
                    const f2 X0 = swp ? a : b;       // bit3=0 slot
                    const f2 X1 = swp ? b : a;       // bit3=1 slot
                    c[r] = kVV*X0 + kVIm*X0.yx + kUU*X1 + kUIp*X1.yx;
                }
            }
        }

        // ===== q = 1..9 single-qubit gates =====
#pragma unroll
        for (int q = 1; q < NQ; ++q) {
            const float ur = readlane_f(cUR, base + q);
            const float ui = readlane_f(cUI, base + q);
            const float vr = readlane_f(cVR, base + q);
            const float vi = readlane_f(cVI, base + q);
            const f2 kUU  = {ur, ur};
            const f2 kUIm = {-ui, ui};
            const f2 kVVn = {-vr, -vr};
            const f2 kVV  = {vr, vr};
            const f2 kVIm = {-vi, vi};
            const f2 kUIp = {ui, -ui};

            if (q < 4) {
                // register-bit qubit: pair stride m within rl (8 regs)
                const int m = 1 << (3 - q);          // 4, 2, 1
#pragma unroll
                for (int r0 = 0; r0 < 8; ++r0) {
                    if (r0 & m) continue;
                    const int r1 = r0 | m;
                    const f2 c0 = c[r0], c1 = c[r1];
                    const f2 c0s = c0.yx, c1s = c1.yx;
                    c[r0] = kUU*c0 + kUIm*c0s + kVVn*c1 + kVIm*c1s;
                    c[r1] = kVV*c0 + kVIm*c0s + kUU*c1  + kUIp*c1s;
                }
            } else {
                // lane-bit qubit: butterfly exchange with lane^M.
                const int  M   = 1 << (9 - q);
                const bool bit = (lane & M) != 0;
                const float Pi = bit ? -ui : ui;
                const float Qr = bit ?  vr : -vr;
                const f2 kUUb = {ur, ur};
                const f2 kPI  = {-Pi, Pi};
                const f2 kQR  = {Qr, Qr};
                const f2 kVIb = {-vi, vi};
#pragma unroll
                for (int r = 0; r < 8; ++r) {
                    const f2 mv = c[r];
                    f2 pv;
                    pv.x = xor_lane(mv.x, M, a4, a16, a32);
                    pv.y = xor_lane(mv.y, M, a4, a16, a32);
                    c[r] = kUUb*mv + kPI*mv.yx + kQR*pv + kVIb*pv.yx;
                }
            }
        }

        // ===== CNOT ring =====
        // CNOT(0,1): ctrl = h (wave-uniform), tgt rl-bit2
        if (h) { SWAPR(0, 4) SWAPR(1, 5) SWAPR(2, 6) SWAPR(3, 7) }
        // CNOT(1,2): ctrl rl-bit2, tgt rl-bit1
        SWAPR(4, 6) SWAPR(5, 7)
        // CNOT(2,3): ctrl rl-bit1, tgt rl-bit0
        SWAPR(2, 3) SWAPR(6, 7)
        // CNOT(3,4)..(8,9) fused: one bpermute per 32-bit value.
#pragma unroll
        for (int r = 0; r < 8; ++r) {
            const int addr = (r & 1) ? addr_odd : addr_even;
            c[r].x = bperm_f(addr, c[r].x);
            c[r].y = bperm_f(addr, c[r].y);
        }
        // CNOT(9,0): ctrl lane-bit0, tgt h -> deferred (next layer's q0
        // operand select; epilogue z0 sign for the final layer).
    }

    // ---- <Z_i> for qubits 0..3 ----
    // Final pending CNOT(9,0): value at (h, lane odd) belongs at half h^1,
    // so z0 sign = -1^(h ^ (lane&1)). Bits rl2..rl0 unaffected.
    const float s0 = ((h ^ (lane & 1)) ? -1.f : 1.f);
    float z0 = 0.f, z1 = 0.f, z2 = 0.f, z3 = 0.f;
#pragma unroll
    for (int r = 0; r < 8; ++r) {
        const float pv = c[r].x * c[r].x + c[r].y * c[r].y;
        z0 += s0 * pv;
        z1 += (r & 4) ? -pv : pv;
        z2 += (r & 2) ? -pv : pv;
        z3 += (r & 1) ? -pv : pv;
    }
#pragma unroll
    for (int m = 1; m < 64; m <<= 1) {
        z0 += xor_lane(z0, m, a4, a16, a32);
        z1 += xor_lane(z1, m, a4, a16, a32);
        z2 += xor_lane(z2, m, a4, a16, a32);
        z3 += xor_lane(z3, m, a4, a16, a32);
    }
    if (lane == 0) {
        red[h * 4 + 0] = z0;
        red[h * 4 + 1] = z1;
        red[h * 4 + 2] = z2;
        red[h * 4 + 3] = z3;
    }
    __syncthreads();
    if (h == 0 && lane == 0) {
        out[wid * 4 + 0] = (red[0] + red[4]) * oscale[0];
        out[wid * 4 + 1] = (red[1] + red[5]) * oscale[1];
        out[wid * 4 + 2] = (red[2] + red[6]) * oscale[2];
        out[wid * 4 + 3] = (red[3] + red[7]) * oscale[3];
    }
#undef SWAPR
}

extern "C" void kernel_launch(void* const* d_in, const int* in_sizes, int n_in,
                              void* d_out, int out_size, void* d_ws, size_t ws_size,
                              hipStream_t stream) {
    const float* x      = (const float*)d_in[0];
    const float* isc    = (const float*)d_in[1];
    const float* w      = (const float*)d_in[2];
    const float* oscale = (const float*)d_in[3];
    float* out = (float*)d_out;

    const int B = in_sizes[0] / OBS;             // 4096 samples
    // one sample per 128-thread block (2 waves), 8192 waves = 8 waves/SIMD
    qsim_kernel<<<B, 128, 0, stream>>>(x, isc, w, oscale, out);
}

// Round 10
// 92.517 us; speedup vs baseline: 1.0703x; 1.0703x over previous
//
#include <hip/hip_runtime.h>

// Batched 10-qubit statevector simulator — one 64-lane wave per sample.
// State: 1024 complex amps; s = (r<<6)|lane; qubit q <-> bit (9-q):
//   qubits 0..3 -> register-index bits (16 complex float2 per lane)
//   qubits 4..9 -> lane bits (butterfly exchanges)
// Per layer per qubit, RY(a)RZ(b)RZ(g)RY(d) fuse into one SU(2)
// U = [[u, -conj(v)],[v, conj(u)]], p=(b+g)/2.
// R1/R2: 50 gate coefficient sets lane-parallel, broadcast via v_readlane.
// R3: __launch_bounds__(256,4); CNOT chain (3,4)..(8,9) fused to one
//     ds_bpermute pass (dest lane d pulls s = (d^(d>>1)) ^ ((r&1)<<5)).
// R4: float2 state -> VOP3P v_pk_fma_f32 (half-rate: 4cyc, same FLOP/cyc as
//     scalar — saves issue slots only).
// R5: masks 1,2 (quad_perm) and 8 (row_ror:8) via DPP on the VALU pipe.
// R7/R8 post-mortem: time ~ total VALU inst-cycles (x1.78); occupancy and
//     DS->VALU shuffling don't help. So R9 DELETES math:
// R9a: layer-0 gates replaced by direct product-state construction
//     (|0..0> -> product state: ~35 complex mults vs ~650 pk ops).
// R9b: final CNOT ring dropped; epilogue measures Z-parities of the
//     pre-ring state: S0={q1..q9}, S1={q0,q1}, S2={q0,q1,q2}, S3={q0..q3}
//     (compile-time register-bit parities x one lane-popcount sign).

constexpr int NQ  = 10;
constexpr int NL  = 5;
constexpr int OBS = 10;

typedef float f2 __attribute__((ext_vector_type(2)));

__device__ __forceinline__ float readlane_f(float v, int l) {
    return __int_as_float(__builtin_amdgcn_readlane(__float_as_int(v), l));
}
__device__ __forceinline__ float bperm_f(int byte_addr, float v) {
    return __int_as_float(__builtin_amdgcn_ds_bpermute(byte_addr, __float_as_int(v)));
}
template <int CTRL>
__device__ __forceinline__ float dpp_f(float v) {
    return __int_as_float(__builtin_amdgcn_update_dpp(
        0, __float_as_int(v), CTRL, 0xF, 0xF, true));
}
// xor-exchange across lanes; M constant after unroll -> branches fold.
__device__ __forceinline__ float xor_lane(float v, int M,
                                          int a4, int a16, int a32) {
    switch (M) {
    case 1:  return dpp_f<0xB1>(v);          // quad_perm [1,0,3,2]
    case 2:  return dpp_f<0x4E>(v);          // quad_perm [2,3,0,1]
    case 8:  return dpp_f<0x128>(v);         // row_ror:8 == lane^8
    case 4:  return bperm_f(a4,  v);
    case 16: return bperm_f(a16, v);
    default: return bperm_f(a32, v);         // 32
    }
}

__global__ __launch_bounds__(256, 4) void qsim_kernel(
    const float* __restrict__ x,       // (B, 10)
    const float* __restrict__ isc,     // (5, 20)
    const float* __restrict__ w,       // (5, 20)
    const float* __restrict__ oscale,  // (4)
    float* __restrict__ out,           // (B, 4)
    int B)
{
    const int lane = threadIdx.x & 63;
    const int wid  = (blockIdx.x * blockDim.x + threadIdx.x) >> 6;
    if (wid >= B) return;

    // ---- lane-parallel gate-coefficient computation (gates 0..49) ----
    float cUR, cUI, cVR, cVI;
    {
        const int g   = (lane < 50) ? lane : 49;
        const int q   = g % 10;
        const int lyr = g / 10;
        const float xq    = x[wid * OBS + q];
        const float alpha = isc[lyr * 2 * NQ + q]      * xq;
        const float beta  = isc[lyr * 2 * NQ + NQ + q] * xq;
        const float gamma = w[lyr * 2 * NQ + q];
        const float delta = w[lyr * 2 * NQ + NQ + q];
        float sa, ca, sp, cp, sd, cd;
        __sincosf(0.5f * alpha,          &sa, &ca);
        __sincosf(0.5f * (beta + gamma), &sp, &cp);
        __sincosf(0.5f * delta,          &sd, &cd);
        const float A = cd * ca, Bt = sd * sa;
        const float C = cd * sa, D  = sd * ca;
        cUR = (A - Bt) * cp;
        cUI = -(A + Bt) * sp;
        cVR = (C + D) * cp;
        cVI = (C - D) * sp;
    }

    // hoisted bpermute byte-addresses (loop-invariant)
    const int a4  = (lane ^ 4)  * 4;
    const int a16 = (lane ^ 16) * 4;
    const int a32 = (lane ^ 32) * 4;
    const int cnot_src  = (lane ^ (lane >> 1));
    const int addr_even = cnot_src * 4;            // r bit0 == 0
    const int addr_odd  = (cnot_src ^ 32) * 4;     // r bit0 == 1 (CNOT(3,4))

    f2 c[16];

    // ===== layer 0: direct product-state construction =====
    // amp(s) = prod_q (bit_q(s) ? v_q : u_q), using gate column (u,v)=U|0>.
    {
        // lane-bit factor: qubits 4..9 <-> lane bits 32..1
        float Lr = 1.f, Li = 0.f;
#pragma unroll
        for (int q = 4; q < 10; ++q) {
            const float ur = readlane_f(cUR, q), ui = readlane_f(cUI, q);
            const float vr = readlane_f(cVR, q), vi = readlane_f(cVI, q);
            const int M = 1 << (9 - q);
            const float fr = (lane & M) ? vr : ur;
            const float fi = (lane & M) ? vi : ui;
            const float nr = Lr * fr - Li * fi;
            const float ni = Lr * fi + Li * fr;
            Lr = nr; Li = ni;
        }
        c[0] = (f2){Lr, Li};
#pragma unroll
        for (int r = 1; r < 16; ++r) c[r] = (f2){0.f, 0.f};
        // register-bit factors: qubit q (0..3) <-> reg bit (3-q), zero-skip
        // doubling (before step for qubit q, only r < m are nonzero).
#pragma unroll
        for (int q = 3; q >= 0; --q) {
            const int m = 1 << (3 - q);
            const float ur = readlane_f(cUR, q), ui = readlane_f(cUI, q);
            const float vr = readlane_f(cVR, q), vi = readlane_f(cVI, q);
#pragma unroll
            for (int r0 = 0; r0 < 16; ++r0) {
                if (r0 >= m) continue;
                const f2 s = c[r0];
                c[r0 | m] = (f2){ s.x*vr - s.y*vi, s.x*vi + s.y*vr };
                c[r0]     = (f2){ s.x*ur - s.y*ui, s.x*ui + s.y*ur };
            }
        }
    }

#define SWAPR(i, j) { f2 _t = c[i]; c[i] = c[j]; c[j] = _t; }

    for (int layer = 0; layer < NL; ++layer) {
        const int base = layer * NQ;   // wave-uniform

        // ---- fused single-qubit unitaries (layer 0 done by construction) ----
        if (layer > 0) {
#pragma unroll
            for (int q = 0; q < NQ; ++q) {
                const float ur = readlane_f(cUR, base + q);
                const float ui = readlane_f(cUI, base + q);
                const float vr = readlane_f(cVR, base + q);
                const float vi = readlane_f(cVI, base + q);
                const f2 kUU  = {ur, ur};
                const f2 kUIm = {-ui, ui};
                const f2 kVVn = {-vr, -vr};
                const f2 kVV  = {vr, vr};
                const f2 kVIm = {-vi, vi};
                const f2 kUIp = {ui, -ui};

                if (q < 4) {
                    // register-bit qubit: pair stride m inside the lane.
                    const int m = 1 << (3 - q);
#pragma unroll
                    for (int r0 = 0; r0 < 16; ++r0) {
                        if (r0 & m) continue;
                        const int r1 = r0 | m;
                        const f2 c0 = c[r0], c1 = c[r1];
                        const f2 c0s = c0.yx, c1s = c1.yx;
                        c[r0] = kUU*c0 + kUIm*c0s + kVVn*c1 + kVIm*c1s;
                        c[r1] = kVV*c0 + kVIm*c0s + kUU*c1  + kUIp*c1s;
                    }
                } else {
                    // lane-bit qubit: butterfly exchange with lane^M.
                    const int  M   = 1 << (9 - q);
                    const bool bit = (lane & M) != 0;
                    const float Pi = bit ? -ui : ui;
                    const float Qr = bit ?  vr : -vr;
                    const f2 kUUb = {ur, ur};
                    const f2 kPI  = {-Pi, Pi};
                    const f2 kQR  = {Qr, Qr};
                    const f2 kVIb = {-vi, vi};
#pragma unroll
                    for (int r = 0; r < 16; ++r) {
                        const f2 mv = c[r];
                        f2 pv;
                        pv.x = xor_lane(mv.x, M, a4, a16, a32);
                        pv.y = xor_lane(mv.y, M, a4, a16, a32);
                        c[r] = kUUb*mv + kPI*mv.yx + kQR*pv + kVIb*pv.yx;
                    }
                }
            }
        }

        // ---- CNOT ring (skipped on last layer; folded into epilogue) ----
        if (layer < NL - 1) {
            // CNOT(0,1): ctrl r-bit3, tgt r-bit2 -> register swap
            SWAPR(8, 12) SWAPR(9, 13) SWAPR(10, 14) SWAPR(11, 15)
            // CNOT(1,2): ctrl r-bit2, tgt r-bit1
            SWAPR(4, 6)  SWAPR(5, 7)  SWAPR(12, 14) SWAPR(13, 15)
            // CNOT(2,3): ctrl r-bit1, tgt r-bit0
            SWAPR(2, 3)  SWAPR(6, 7)  SWAPR(10, 11) SWAPR(14, 15)
            // CNOT(3,4)..(8,9) fused: one bpermute per 32-bit value.
#pragma unroll
            for (int r = 0; r < 16; ++r) {
                const int addr = (r & 1) ? addr_odd : addr_even;
                c[r].x = bperm_f(addr, c[r].x);
                c[r].y = bperm_f(addr, c[r].y);
            }
            // CNOT(9,0): ctrl lane-bit0, tgt r-bit3 -> cond register swap
            const bool ctl = (lane & 1) != 0;
#pragma unroll
            for (int r = 0; r < 8; ++r) {
                const f2 t0 = c[r], t1 = c[r + 8];
                c[r]     = ctl ? t1 : t0;
                c[r + 8] = ctl ? t0 : t1;
            }
        }
    }

    // ---- epilogue: <Z_i> after the (virtual) final ring ----
    // (Cb)_0 = q1+..+q9 -> reg bits r2,r1,r0 (+ all 6 lane bits)
    // (Cb)_1 = q0+q1 -> r3,r2 ; (Cb)_2 -> r3,r2,r1 ; (Cb)_3 -> r3..r0
    const float sL = (__popc(lane) & 1) ? -1.f : 1.f;
    float z0 = 0.f, z1 = 0.f, z2 = 0.f, z3 = 0.f;
#pragma unroll
    for (int r = 0; r < 16; ++r) {
        const float pv  = c[r].x * c[r].x + c[r].y * c[r].y;
        const float pvl = sL * pv;
        z0 += (__popc(r & 7)  & 1) ? -pvl : pvl;
        z1 += (__popc(r & 12) & 1) ? -pv  : pv;
        z2 += (__popc(r & 14) & 1) ? -pv  : pv;
        z3 += (__popc(r & 15) & 1) ? -pv  : pv;
    }
#pragma unroll
    for (int m = 1; m < 64; m <<= 1) {
        z0 += xor_lane(z0, m, a4, a16, a32);
        z1 += xor_lane(z1, m, a4, a16, a32);
        z2 += xor_lane(z2, m, a4, a16, a32);
        z3 += xor_lane(z3, m, a4, a16, a32);
    }
    if (lane == 0) {
        out[wid * 4 + 0] = z0 * oscale[0];
        out[wid * 4 + 1] = z1 * oscale[1];
        out[wid * 4 + 2] = z2 * oscale[2];
        out[wid * 4 + 3] = z3 * oscale[3];
    }
#undef SWAPR
}

extern "C" void kernel_launch(void* const* d_in, const int* in_sizes, int n_in,
                              void* d_out, int out_size, void* d_ws, size_t ws_size,
                              hipStream_t stream) {
    const float* x      = (const float*)d_in[0];
    const float* isc    = (const float*)d_in[1];
    const float* w      = (const float*)d_in[2];
    const float* oscale = (const float*)d_in[3];
    float* out = (float*)d_out;

    const int B = in_sizes[0] / OBS;             // 4096
    const int threads = 256;                     // 4 waves -> 4 samples per block
    const int blocks = (B * 64 + threads - 1) / threads;
    qsim_kernel<<<blocks, threads, 0, stream>>>(x, isc, w, oscale, out, B);
}

// Round 11
// 91.960 us; speedup vs baseline: 1.0767x; 1.0061x over previous
//
#include <hip/hip_runtime.h>

// Batched 10-qubit statevector simulator — one 64-lane wave per sample.
// State: 1024 complex amps; s = (r<<6)|lane; qubit q <-> bit (9-q):
//   qubits 0..3 -> register-index bits (16 complex float2 per lane)
//   qubits 4..9 -> lane bits (butterfly exchanges)
// Per layer per qubit, RY(a)RZ(b)RZ(g)RY(d) fuse into one SU(2)
// U = [[u, -conj(v)],[v, conj(u)]], p=(b+g)/2.
// R1/R2: 50 gate coefficient sets lane-parallel, broadcast via v_readlane.
// R3: __launch_bounds__(256,4); CNOT chain (3,4)..(8,9) fused to one
//     ds_bpermute pass (dest lane d pulls s = (d^(d>>1)) ^ ((r&1)<<5)).
// R4: float2 state -> VOP3P v_pk_fma_f32.
// R5: masks 1,2 (quad_perm) and 8 (row_ror:8) via DPP on the VALU pipe.
// R9: layer-0 gates -> direct product-state construction; final CNOT ring
//     folded into epilogue Z-parities.
// R5/R7/R8/R9 post-mortem -> unified model: the per-CU DS pipe is the
//     co-limiter (~520 wave64 bpermutes x 16 waves/CU at ~8-12cyc saturates
//     it; extra waves (R8) made it WORSE; DS->DPP 1:1 (R5) was the big win).
// R10: mask-4 exchange = 2-DPP chain (quad_perm xor3 0x1B + row_half_mirror
//     xor7 0x141): q7 gates + epilogue m=4 leave the DS pipe.
//     DS/wave 524 -> 392. Ring deferral checked algebraically: spreads masks,
//     nets +32 DS — rejected.

constexpr int NQ  = 10;
constexpr int NL  = 5;
constexpr int OBS = 10;

typedef float f2 __attribute__((ext_vector_type(2)));

__device__ __forceinline__ float readlane_f(float v, int l) {
    return __int_as_float(__builtin_amdgcn_readlane(__float_as_int(v), l));
}
__device__ __forceinline__ float bperm_f(int byte_addr, float v) {
    return __int_as_float(__builtin_amdgcn_ds_bpermute(byte_addr, __float_as_int(v)));
}
template <int CTRL>
__device__ __forceinline__ float dpp_f(float v) {
    return __int_as_float(__builtin_amdgcn_update_dpp(
        0, __float_as_int(v), CTRL, 0xF, 0xF, true));
}
// xor-exchange across lanes; M constant after unroll -> branches fold.
__device__ __forceinline__ float xor_lane(float v, int M, int a16, int a32) {
    switch (M) {
    case 1:  return dpp_f<0xB1>(v);            // quad_perm [1,0,3,2]
    case 2:  return dpp_f<0x4E>(v);            // quad_perm [2,3,0,1]
    case 8:  return dpp_f<0x128>(v);           // row_ror:8 == lane^8
    case 4:  return dpp_f<0x141>(dpp_f<0x1B>(v)); // xor3 (quad rev) ∘ xor7 (half-mirror) = xor4
    case 16: return bperm_f(a16, v);
    default: return bperm_f(a32, v);           // 32
    }
}

__global__ __launch_bounds__(256, 4) void qsim_kernel(
    const float* __restrict__ x,       // (B, 10)
    const float* __restrict__ isc,     // (5, 20)
    const float* __restrict__ w,       // (5, 20)
    const float* __restrict__ oscale,  // (4)
    float* __restrict__ out,           // (B, 4)
    int B)
{
    const int lane = threadIdx.x & 63;
    const int wid  = (blockIdx.x * blockDim.x + threadIdx.x) >> 6;
    if (wid >= B) return;

    // ---- lane-parallel gate-coefficient computation (gates 0..49) ----
    float cUR, cUI, cVR, cVI;
    {
        const int g   = (lane < 50) ? lane : 49;
        const int q   = g % 10;
        const int lyr = g / 10;
        const float xq    = x[wid * OBS + q];
        const float alpha = isc[lyr * 2 * NQ + q]      * xq;
        const float beta  = isc[lyr * 2 * NQ + NQ + q] * xq;
        const float gamma = w[lyr * 2 * NQ + q];
        const float delta = w[lyr * 2 * NQ + NQ + q];
        float sa, ca, sp, cp, sd, cd;
        __sincosf(0.5f * alpha,          &sa, &ca);
        __sincosf(0.5f * (beta + gamma), &sp, &cp);
        __sincosf(0.5f * delta,          &sd, &cd);
        const float A = cd * ca, Bt = sd * sa;
        const float C = cd * sa, D  = sd * ca;
        cUR = (A - Bt) * cp;
        cUI = -(A + Bt) * sp;
        cVR = (C + D) * cp;
        cVI = (C - D) * sp;
    }

    // hoisted bpermute byte-addresses (loop-invariant)
    const int a16 = (lane ^ 16) * 4;
    const int a32 = (lane ^ 32) * 4;
    const int cnot_src  = (lane ^ (lane >> 1));
    const int addr_even = cnot_src * 4;            // r bit0 == 0
    const int addr_odd  = (cnot_src ^ 32) * 4;     // r bit0 == 1 (CNOT(3,4))

    f2 c[16];

    // ===== layer 0: direct product-state construction =====
    // amp(s) = prod_q (bit_q(s) ? v_q : u_q), using gate column (u,v)=U|0>.
    {
        // lane-bit factor: qubits 4..9 <-> lane bits 32..1
        float Lr = 1.f, Li = 0.f;
#pragma unroll
        for (int q = 4; q < 10; ++q) {
            const float ur = readlane_f(cUR, q), ui = readlane_f(cUI, q);
            const float vr = readlane_f(cVR, q), vi = readlane_f(cVI, q);
            const int M = 1 << (9 - q);
            const float fr = (lane & M) ? vr : ur;
            const float fi = (lane & M) ? vi : ui;
            const float nr = Lr * fr - Li * fi;
            const float ni = Lr * fi + Li * fr;
            Lr = nr; Li = ni;
        }
        c[0] = (f2){Lr, Li};
#pragma unroll
        for (int r = 1; r < 16; ++r) c[r] = (f2){0.f, 0.f};
        // register-bit factors: qubit q (0..3) <-> reg bit (3-q), zero-skip
        // doubling (before step for qubit q, only r < m are nonzero).
#pragma unroll
        for (int q = 3; q >= 0; --q) {
            const int m = 1 << (3 - q);
            const float ur = readlane_f(cUR, q), ui = readlane_f(cUI, q);
            const float vr = readlane_f(cVR, q), vi = readlane_f(cVI, q);
#pragma unroll
            for (int r0 = 0; r0 < 16; ++r0) {
                if (r0 >= m) continue;
                const f2 s = c[r0];
                c[r0 | m] = (f2){ s.x*vr - s.y*vi, s.x*vi + s.y*vr };
                c[r0]     = (f2){ s.x*ur - s.y*ui, s.x*ui + s.y*ur };
            }
        }
    }

#define SWAPR(i, j) { f2 _t = c[i]; c[i] = c[j]; c[j] = _t; }

    for (int layer = 0; layer < NL; ++layer) {
        const int base = layer * NQ;   // wave-uniform

        // ---- fused single-qubit unitaries (layer 0 done by construction) ----
        if (layer > 0) {
#pragma unroll
            for (int q = 0; q < NQ; ++q) {
                const float ur = readlane_f(cUR, base + q);
                const float ui = readlane_f(cUI, base + q);
                const float vr = readlane_f(cVR, base + q);
                const float vi = readlane_f(cVI, base + q);
                const f2 kUU  = {ur, ur};
                const f2 kUIm = {-ui, ui};
                const f2 kVVn = {-vr, -vr};
                const f2 kVV  = {vr, vr};
                const f2 kVIm = {-vi, vi};
                const f2 kUIp = {ui, -ui};

                if (q < 4) {
                    // register-bit qubit: pair stride m inside the lane.
                    const int m = 1 << (3 - q);
#pragma unroll
                    for (int r0 = 0; r0 < 16; ++r0) {
                        if (r0 & m) continue;
                        const int r1 = r0 | m;
                        const f2 c0 = c[r0], c1 = c[r1];
                        const f2 c0s = c0.yx, c1s = c1.yx;
                        c[r0] = kUU*c0 + kUIm*c0s + kVVn*c1 + kVIm*c1s;
                        c[r1] = kVV*c0 + kVIm*c0s + kUU*c1  + kUIp*c1s;
                    }
                } else {
                    // lane-bit qubit: butterfly exchange with lane^M.
                    const int  M   = 1 << (9 - q);
                    const bool bit = (lane & M) != 0;
                    const float Pi = bit ? -ui : ui;
                    const float Qr = bit ?  vr : -vr;
                    const f2 kUUb = {ur, ur};
                    const f2 kPI  = {-Pi, Pi};
                    const f2 kQR  = {Qr, Qr};
                    const f2 kVIb = {-vi, vi};
#pragma unroll
                    for (int r = 0; r < 16; ++r) {
                        const f2 mv = c[r];
                        f2 pv;
                        pv.x = xor_lane(mv.x, M, a16, a32);
                        pv.y = xor_lane(mv.y, M, a16, a32);
                        c[r] = kUUb*mv + kPI*mv.yx + kQR*pv + kVIb*pv.yx;
                    }
                }
            }
        }

        // ---- CNOT ring (skipped on last layer; folded into epilogue) ----
        if (layer < NL - 1) {
            // CNOT(0,1): ctrl r-bit3, tgt r-bit2 -> register swap
            SWAPR(8, 12) SWAPR(9, 13) SWAPR(10, 14) SWAPR(11, 15)
            // CNOT(1,2): ctrl r-bit2, tgt r-bit1
            SWAPR(4, 6)  SWAPR(5, 7)  SWAPR(12, 14) SWAPR(13, 15)
            // CNOT(2,3): ctrl r-bit1, tgt r-bit0
            SWAPR(2, 3)  SWAPR(6, 7)  SWAPR(10, 11) SWAPR(14, 15)
            // CNOT(3,4)..(8,9) fused: one bpermute per 32-bit value.
#pragma unroll
            for (int r = 0; r < 16; ++r) {
                const int addr = (r & 1) ? addr_odd : addr_even;
                c[r].x = bperm_f(addr, c[r].x);
                c[r].y = bperm_f(addr, c[r].y);
            }
            // CNOT(9,0): ctrl lane-bit0, tgt r-bit3 -> cond register swap
            const bool ctl = (lane & 1) != 0;
#pragma unroll
            for (int r = 0; r < 8; ++r) {
                const f2 t0 = c[r], t1 = c[r + 8];
                c[r]     = ctl ? t1 : t0;
                c[r + 8] = ctl ? t0 : t1;
            }
        }
    }

    // ---- epilogue: <Z_i> after the (virtual) final ring ----
    // (Cb)_0 = q1+..+q9 -> reg bits r2,r1,r0 (+ all 6 lane bits)
    // (Cb)_1 = q0+q1 -> r3,r2 ; (Cb)_2 -> r3,r2,r1 ; (Cb)_3 -> r3..r0
    const float sL = (__popc(lane) & 1) ? -1.f : 1.f;
    float z0 = 0.f, z1 = 0.f, z2 = 0.f, z3 = 0.f;
#pragma unroll
    for (int r = 0; r < 16; ++r) {
        const float pv  = c[r].x * c[r].x + c[r].y * c[r].y;
        const float pvl = sL * pv;
        z0 += (__popc(r & 7)  & 1) ? -pvl : pvl;
        z1 += (__popc(r & 12) & 1) ? -pv  : pv;
        z2 += (__popc(r & 14) & 1) ? -pv  : pv;
        z3 += (__popc(r & 15) & 1) ? -pv  : pv;
    }
#pragma unroll
    for (int m = 1; m < 64; m <<= 1) {
        z0 += xor_lane(z0, m, a16, a32);
        z1 += xor_lane(z1, m, a16, a32);
        z2 += xor_lane(z2, m, a16, a32);
        z3 += xor_lane(z3, m, a16, a32);
    }
    if (lane == 0) {
        out[wid * 4 + 0] = z0 * oscale[0];
        out[wid * 4 + 1] = z1 * oscale[1];
        out[wid * 4 + 2] = z2 * oscale[2];
        out[wid * 4 + 3] = z3 * oscale[3];
    }
#undef SWAPR
}

extern "C" void kernel_launch(void* const* d_in, const int* in_sizes, int n_in,
                              void* d_out, int out_size, void* d_ws, size_t ws_size,
                              hipStream_t stream) {
    const float* x      = (const float*)d_in[0];
    const float* isc    = (const float*)d_in[1];
    const float* w      = (const float*)d_in[2];
    const float* oscale = (const float*)d_in[3];
    float* out = (float*)d_out;

    const int B = in_sizes[0] / OBS;             // 4096
    const int threads = 256;                     // 4 waves -> 4 samples per block
    const int blocks = (B * 64 + threads - 1) / threads;
    qsim_kernel<<<blocks, threads, 0, stream>>>(x, isc, w, oscale, out, B);
}

// Round 12
// 90.906 us; speedup vs baseline: 1.0892x; 1.0116x over previous
//
#include <hip/hip_runtime.h>

// Batched 10-qubit statevector simulator — one 64-lane wave per sample.
// State: 1024 complex amps; s = (r<<6)|lane; qubit q <-> bit (9-q):
//   qubits 0..3 -> register-index bits (16 complex float2 per lane)
//   qubits 4..9 -> lane bits (butterfly exchanges)
// Per layer per qubit, RY(a)RZ(b)RZ(g)RY(d) fuse into one SU(2)
// U = [[u, -conj(v)],[v, conj(u)]], p=(b+g)/2.
// R1/R2: 50 gate coefficient sets lane-parallel, broadcast via v_readlane.
// R3: __launch_bounds__(256,4); CNOT chain (3,4)..(8,9) fused to one
//     ds_bpermute pass (dest lane d pulls s = (d^(d>>1)) ^ ((r&1)<<5)).
// R4: float2 state -> VOP3P v_pk_fma_f32.
// R5: masks 1,2 (quad_perm) and 8 (row_ror:8) via DPP on the VALU pipe.
// R9: layer-0 -> product-state construction; final ring -> epilogue parities.
// R10: mask-4 = 2-DPP chain (0x1B then 0x141). DS/wave ~390.
// R11: DS-phase STAGGERING. All 16 waves/CU previously hit the DS-heavy
//     gates (q4/q5 + ring) simultaneously -> synchronized lgkmcnt stalls on
//     the one shared LDS unit (the ~37% non-VALU time; also why R8's extra
//     waves hurt). The 10 per-layer unitaries commute (distinct qubits), so
//     even waves apply q0..q9 and odd waves q9..q0 — DS load decorrelates
//     across waves at zero math cost.

constexpr int NQ  = 10;
constexpr int NL  = 5;
constexpr int OBS = 10;

typedef float f2 __attribute__((ext_vector_type(2)));

__device__ __forceinline__ float readlane_f(float v, int l) {
    return __int_as_float(__builtin_amdgcn_readlane(__float_as_int(v), l));
}
__device__ __forceinline__ float bperm_f(int byte_addr, float v) {
    return __int_as_float(__builtin_amdgcn_ds_bpermute(byte_addr, __float_as_int(v)));
}
template <int CTRL>
__device__ __forceinline__ float dpp_f(float v) {
    return __int_as_float(__builtin_amdgcn_update_dpp(
        0, __float_as_int(v), CTRL, 0xF, 0xF, true));
}
// xor-exchange across lanes; M compile-time -> branches fold.
__device__ __forceinline__ float xor_lane(float v, int M, int a16, int a32) {
    switch (M) {
    case 1:  return dpp_f<0xB1>(v);               // quad_perm [1,0,3,2]
    case 2:  return dpp_f<0x4E>(v);               // quad_perm [2,3,0,1]
    case 8:  return dpp_f<0x128>(v);              // row_ror:8 == lane^8
    case 4:  return dpp_f<0x141>(dpp_f<0x1B>(v)); // xor3 ∘ xor7 = xor4
    case 16: return bperm_f(a16, v);
    default: return bperm_f(a32, v);              // 32
    }
}

// fused SU(2) gate on qubit Q (compile-time), packed-f32 math
template <int Q>
__device__ __forceinline__ void apply_gate(f2* c, int lane,
                                           float ur, float ui,
                                           float vr, float vi,
                                           int a16, int a32) {
    const f2 kUU  = {ur, ur};
    const f2 kUIm = {-ui, ui};
    const f2 kVVn = {-vr, -vr};
    const f2 kVV  = {vr, vr};
    const f2 kVIm = {-vi, vi};
    const f2 kUIp = {ui, -ui};
    if constexpr (Q < 4) {
        // register-bit qubit: pair stride m inside the lane.
        constexpr int m = 1 << (3 - Q);
#pragma unroll
        for (int r0 = 0; r0 < 16; ++r0) {
            if (r0 & m) continue;
            const int r1 = r0 | m;
            const f2 c0 = c[r0], c1 = c[r1];
            const f2 c0s = c0.yx, c1s = c1.yx;
            c[r0] = kUU*c0 + kUIm*c0s + kVVn*c1 + kVIm*c1s;
            c[r1] = kVV*c0 + kVIm*c0s + kUU*c1  + kUIp*c1s;
        }
    } else {
        // lane-bit qubit: butterfly exchange with lane^M.
        constexpr int M = 1 << (9 - Q);
        const bool bit = (lane & M) != 0;
        const float Pi = bit ? -ui : ui;
        const float Qr = bit ?  vr : -vr;
        const f2 kUUb = {ur, ur};
        const f2 kPI  = {-Pi, Pi};
        const f2 kQR  = {Qr, Qr};
        const f2 kVIb = {-vi, vi};
#pragma unroll
        for (int r = 0; r < 16; ++r) {
            const f2 mv = c[r];
            f2 pv;
            pv.x = xor_lane(mv.x, M, a16, a32);
            pv.y = xor_lane(mv.y, M, a16, a32);
            c[r] = kUUb*mv + kPI*mv.yx + kQR*pv + kVIb*pv.yx;
        }
    }
}

__global__ __launch_bounds__(256, 4) void qsim_kernel(
    const float* __restrict__ x,       // (B, 10)
    const float* __restrict__ isc,     // (5, 20)
    const float* __restrict__ w,       // (5, 20)
    const float* __restrict__ oscale,  // (4)
    float* __restrict__ out,           // (B, 4)
    int B)
{
    const int lane = threadIdx.x & 63;
    const int wid  = (blockIdx.x * blockDim.x + threadIdx.x) >> 6;
    if (wid >= B) return;

    // ---- lane-parallel gate-coefficient computation (gates 0..49) ----
    float cUR, cUI, cVR, cVI;
    {
        const int g   = (lane < 50) ? lane : 49;
        const int q   = g % 10;
        const int lyr = g / 10;
        const float xq    = x[wid * OBS + q];
        const float alpha = isc[lyr * 2 * NQ + q]      * xq;
        const float beta  = isc[lyr * 2 * NQ + NQ + q] * xq;
        const float gamma = w[lyr * 2 * NQ + q];
        const float delta = w[lyr * 2 * NQ + NQ + q];
        float sa, ca, sp, cp, sd, cd;
        __sincosf(0.5f * alpha,          &sa, &ca);
        __sincosf(0.5f * (beta + gamma), &sp, &cp);
        __sincosf(0.5f * delta,          &sd, &cd);
        const float A = cd * ca, Bt = sd * sa;
        const float C = cd * sa, D  = sd * ca;
        cUR = (A - Bt) * cp;
        cUI = -(A + Bt) * sp;
        cVR = (C + D) * cp;
        cVI = (C - D) * sp;
    }

    // hoisted bpermute byte-addresses (loop-invariant)
    const int a16 = (lane ^ 16) * 4;
    const int a32 = (lane ^ 32) * 4;
    const int cnot_src  = (lane ^ (lane >> 1));
    const int addr_even = cnot_src * 4;            // r bit0 == 0
    const int addr_odd  = (cnot_src ^ 32) * 4;     // r bit0 == 1 (CNOT(3,4))

    const bool rev = (wid & 1) != 0;   // wave-uniform gate-order phase

    f2 c[16];

    // ===== layer 0: direct product-state construction =====
    // amp(s) = prod_q (bit_q(s) ? v_q : u_q), using gate column (u,v)=U|0>.
    {
        float Lr = 1.f, Li = 0.f;
#pragma unroll
        for (int q = 4; q < 10; ++q) {
            const float ur = readlane_f(cUR, q), ui = readlane_f(cUI, q);
            const float vr = readlane_f(cVR, q), vi = readlane_f(cVI, q);
            const int M = 1 << (9 - q);
            const float fr = (lane & M) ? vr : ur;
            const float fi = (lane & M) ? vi : ui;
            const float nr = Lr * fr - Li * fi;
            const float ni = Lr * fi + Li * fr;
            Lr = nr; Li = ni;
        }
        c[0] = (f2){Lr, Li};
#pragma unroll
        for (int r = 1; r < 16; ++r) c[r] = (f2){0.f, 0.f};
#pragma unroll
        for (int q = 3; q >= 0; --q) {
            const int m = 1 << (3 - q);
            const float ur = readlane_f(cUR, q), ui = readlane_f(cUI, q);
            const float vr = readlane_f(cVR, q), vi = readlane_f(cVI, q);
#pragma unroll
            for (int r0 = 0; r0 < 16; ++r0) {
                if (r0 >= m) continue;
                const f2 s = c[r0];
                c[r0 | m] = (f2){ s.x*vr - s.y*vi, s.x*vi + s.y*vr };
                c[r0]     = (f2){ s.x*ur - s.y*ui, s.x*ui + s.y*ur };
            }
        }
    }

#define SWAPR(i, j) { f2 _t = c[i]; c[i] = c[j]; c[j] = _t; }
#define G(Q) { const float ur = readlane_f(cUR, base + Q);                 \
               const float ui = readlane_f(cUI, base + Q);                 \
               const float vr = readlane_f(cVR, base + Q);                 \
               const float vi = readlane_f(cVI, base + Q);                 \
               apply_gate<Q>(c, lane, ur, ui, vr, vi, a16, a32); }

    for (int layer = 0; layer < NL; ++layer) {
        const int base = layer * NQ;   // wave-uniform

        // ---- fused single-qubit unitaries (layer 0 done by construction).
        // Gates on distinct qubits commute: even waves ascend, odd waves
        // descend, staggering the DS-heavy gates (q4/q5) across the CU.
        if (layer > 0) {
            if (!rev) {
                G(0) G(1) G(2) G(3) G(4) G(5) G(6) G(7) G(8) G(9)
            } else {
                G(9) G(8) G(7) G(6) G(5) G(4) G(3) G(2) G(1) G(0)
            }
        }

        // ---- CNOT ring (skipped on last layer; folded into epilogue) ----
        if (layer < NL - 1) {
            // CNOT(0,1): ctrl r-bit3, tgt r-bit2 -> register swap
            SWAPR(8, 12) SWAPR(9, 13) SWAPR(10, 14) SWAPR(11, 15)
            // CNOT(1,2): ctrl r-bit2, tgt r-bit1
            SWAPR(4, 6)  SWAPR(5, 7)  SWAPR(12, 14) SWAPR(13, 15)
            // CNOT(2,3): ctrl r-bit1, tgt r-bit0
            SWAPR(2, 3)  SWAPR(6, 7)  SWAPR(10, 11) SWAPR(14, 15)
            // CNOT(3,4)..(8,9) fused: one bpermute per 32-bit value.
#pragma unroll
            for (int r = 0; r < 16; ++r) {
                const int addr = (r & 1) ? addr_odd : addr_even;
                c[r].x = bperm_f(addr, c[r].x);
                c[r].y = bperm_f(addr, c[r].y);
            }
            // CNOT(9,0): ctrl lane-bit0, tgt r-bit3 -> cond register swap
            const bool ctl = (lane & 1) != 0;
#pragma unroll
            for (int r = 0; r < 8; ++r) {
                const f2 t0 = c[r], t1 = c[r + 8];
                c[r]     = ctl ? t1 : t0;
                c[r + 8] = ctl ? t0 : t1;
            }
        }
    }

    // ---- epilogue: <Z_i> after the (virtual) final ring ----
    // (Cb)_0 = q1+..+q9 -> reg bits r2,r1,r0 (+ all 6 lane bits)
    // (Cb)_1 = q0+q1 -> r3,r2 ; (Cb)_2 -> r3,r2,r1 ; (Cb)_3 -> r3..r0
    const float sL = (__popc(lane) & 1) ? -1.f : 1.f;
    float z0 = 0.f, z1 = 0.f, z2 = 0.f, z3 = 0.f;
#pragma unroll
    for (int r = 0; r < 16; ++r) {
        const float pv  = c[r].x * c[r].x + c[r].y * c[r].y;
        const float pvl = sL * pv;
        z0 += (__popc(r & 7)  & 1) ? -pvl : pvl;
        z1 += (__popc(r & 12) & 1) ? -pv  : pv;
        z2 += (__popc(r & 14) & 1) ? -pv  : pv;
        z3 += (__popc(r & 15) & 1) ? -pv  : pv;
    }
#pragma unroll
    for (int m = 1; m < 64; m <<= 1) {
        z0 += xor_lane(z0, m, a16, a32);
        z1 += xor_lane(z1, m, a16, a32);
        z2 += xor_lane(z2, m, a16, a32);
        z3 += xor_lane(z3, m, a16, a32);
    }
    if (lane == 0) {
        out[wid * 4 + 0] = z0 * oscale[0];
        out[wid * 4 + 1] = z1 * oscale[1];
        out[wid * 4 + 2] = z2 * oscale[2];
        out[wid * 4 + 3] = z3 * oscale[3];
    }
#undef SWAPR
#undef G
}

extern "C" void kernel_launch(void* const* d_in, const int* in_sizes, int n_in,
                              void* d_out, int out_size, void* d_ws, size_t ws_size,
                              hipStream_t stream) {
    const float* x      = (const float*)d_in[0];
    const float* isc    = (const float*)d_in[1];
    const float* w      = (const float*)d_in[2];
    const float* oscale = (const float*)d_in[3];
    float* out = (float*)d_out;

    const int B = in_sizes[0] / OBS;             // 4096
    const int threads = 256;                     // 4 waves -> 4 samples per block
    const int blocks = (B * 64 + threads - 1) / threads;
    qsim_kernel<<<blocks, threads, 0, stream>>>(x, isc, w, oscale, out, B);
}